// Round 1
// baseline (82.048 us; speedup 1.0000x reference)
//
#include <hip/hip_runtime.h>

// Leaky-integrate-and-fire scan, 2001 steps over 16x2048 fp32 neurons.
// Outputs (concatenated flat in d_out, all fp32):
//   s_last [N], v_last [N], v_t [T*N], s_t [T*N]   with N=32768, T=2001.
// ~525 MB of coalesced writes -> pure HBM-write-bound kernel.

#define T_STEPS 2001

__global__ __launch_bounds__(128) void lif_scan_kernel(
    const float* __restrict__ x,
    float* __restrict__ s_last,
    float* __restrict__ v_last,
    float* __restrict__ v_t,
    float* __restrict__ s_t,
    int n)
{
    const int i = blockIdx.x * blockDim.x + threadIdx.x;
    if (i >= n) return;

    // Constants pinned to the fp32 roundings the reference uses:
    // LEAK = float(0.95); DRIVE = float(1.0 - 0.95) -> same bits as 0.05f.
    const float LEAK   = 0.95f;
    const float DRIVE  = 0.05f;
    const float THRESH = 0.3f;

    const float xv    = x[i];
    // Hoisted: (1-LEAK)*x is the identical product every step (bit-exact hoist).
    // __fmul_rn / __fadd_rn forbid FMA contraction so we match plain
    // mul-then-add fp32 rounding of the host reference.
    const float drive = __fmul_rn(DRIVE, xv);

    float v    = 0.0f;
    float spkf = 0.0f;
    size_t off = (size_t)i;

    #pragma unroll 4
    for (int t = 0; t < T_STEPS; ++t) {
        v = __fadd_rn(__fmul_rn(LEAK, v), drive);  // leak + drive
        const bool spk = v > THRESH;               // fire
        v    = spk ? 0.0f : v;                     // hard reset (stored value)
        spkf = spk ? 1.0f : 0.0f;
        v_t[off] = v;
        s_t[off] = spkf;
        off += (size_t)n;
    }

    s_last[i] = spkf;   // s_t[-1]
    v_last[i] = v;      // carry after final step
}

extern "C" void kernel_launch(void* const* d_in, const int* in_sizes, int n_in,
                              void* d_out, int out_size, void* d_ws, size_t ws_size,
                              hipStream_t stream)
{
    const float* x = (const float*)d_in[0];
    const int n = in_sizes[0];          // 16*2048 = 32768

    float* out    = (float*)d_out;
    float* s_last = out;
    float* v_last = out + n;
    float* v_t    = out + 2 * (size_t)n;
    float* s_t    = out + 2 * (size_t)n + (size_t)T_STEPS * (size_t)n;

    const int block = 128;
    const int grid  = (n + block - 1) / block;   // 256 blocks -> 1 per CU
    lif_scan_kernel<<<grid, block, 0, stream>>>(x, s_last, v_last, v_t, s_t, n);
}